// Round 4
// baseline (204.487 us; speedup 1.0000x reference)
//
#include <hip/hip_runtime.h>
#include <hip/hip_bf16.h>

#define BB   2
#define NNN  2048
#define DIN  256
#define HH   8
#define DHD  32
#define NW   (NNN/64)   // 32 mask words per row

typedef __attribute__((ext_vector_type(8))) short short8;
typedef __attribute__((ext_vector_type(4))) float f32x4;
typedef __attribute__((ext_vector_type(16))) float f32x16;

#if __has_builtin(__builtin_amdgcn_exp2f)
#define EXP2(x) __builtin_amdgcn_exp2f(x)
#else
#define EXP2(x) exp2f(x)
#endif

__device__ __forceinline__ unsigned int pk2(float a, float b) {
  union { __hip_bfloat162 h2; unsigned int u; } cv;
  cv.h2 = __float22bfloat162_rn(float2{a, b});   // v_cvt_pk_bf16_f32, RNE
  return cv.u;
}
__device__ __forceinline__ unsigned short f2bf(float f) {
  unsigned int u = __float_as_uint(f);
  u += 0x7fffu + ((u >> 16) & 1u);
  return (unsigned short)(u >> 16);
}

#define QSCALE (0.17677669529663687f * 1.4426950408889634f)  // 1/sqrt(32) * log2(e)

// ---------------- fused prep ----------------
// blocks [0,32768): adj -> bitmask | [32768,33536): QKV MFMA gemm (inline W cast)
// [33536,33600): Wo -> Wo^T
__global__ __launch_bounds__(256) void prep(
    const float* __restrict__ adj, unsigned long long* __restrict__ Mk,
    const float* __restrict__ x, const float* __restrict__ Wq,
    const float* __restrict__ Wk, const float* __restrict__ Wv,
    unsigned short* __restrict__ Qb, unsigned short* __restrict__ Kb,
    unsigned short* __restrict__ Vt,
    const float* __restrict__ Wo, float* __restrict__ Wot) {
  __shared__ float tl[32][33];
  const int bid = blockIdx.x, tid = threadIdx.x;

  if (bid < 32768) {                       // ---- adjacency -> 64-bit masks ----
    size_t i = (size_t)bid * 256 + tid;
    float v = adj[i];
    unsigned long long bm = __ballot(v != 0.0f);
    if ((tid & 63) == 0) Mk[i >> 6] = bm;
  } else if (bid < 33536) {                // ---- QKV projection, 1 wave-task each ----
    const int lane = tid & 63, col = lane & 15, quad = lane >> 4;
    const int task = (bid - 32768) * 4 + (tid >> 6);   // 3072 tasks
    const int y = task % 12;
    const int row0 = (task / 12) * 16;
    const int mat = y >> 2, ocb = (y & 3) * 64;
    const float* W = (mat == 0) ? Wq : (mat == 1) ? Wk : Wv;

    f32x4 acc[4];
    #pragma unroll
    for (int c = 0; c < 4; ++c) acc[c] = (f32x4){0.f, 0.f, 0.f, 0.f};

    #pragma unroll
    for (int kk = 0; kk < 8; ++kk) {
      const float* xp = x + (size_t)(row0 + col) * DIN + kk * 32 + quad * 8;
      float4 a0 = *(const float4*)xp, a1 = *(const float4*)(xp + 4);
      union { short8 s; unsigned int u[4]; } af;
      af.u[0] = pk2(a0.x, a0.y); af.u[1] = pk2(a0.z, a0.w);
      af.u[2] = pk2(a1.x, a1.y); af.u[3] = pk2(a1.z, a1.w);
      #pragma unroll
      for (int c = 0; c < 4; ++c) {
        const float* wp = W + (size_t)(ocb + c * 16 + col) * DIN + kk * 32 + quad * 8;
        float4 b0 = *(const float4*)wp, b1 = *(const float4*)(wp + 4);
        union { short8 s; unsigned int u[4]; } bw;
        bw.u[0] = pk2(b0.x, b0.y); bw.u[1] = pk2(b0.z, b0.w);
        bw.u[2] = pk2(b1.x, b1.y); bw.u[3] = pk2(b1.z, b1.w);
        acc[c] = __builtin_amdgcn_mfma_f32_16x16x32_bf16(af.s, bw.s, acc[c], 0, 0, 0);
      }
    }
    const float scale = (mat == 0) ? QSCALE : 1.0f;
    #pragma unroll
    for (int c = 0; c < 4; ++c) {
      int oc = ocb + c * 16 + col, h = oc >> 5, dh = oc & 31;
      #pragma unroll
      for (int r = 0; r < 4; ++r) {
        int row = row0 + quad * 4 + r;
        int b = row >> 11, n = row & (NNN - 1);
        unsigned short val = f2bf(acc[c][r] * scale);
        if (mat == 2)       Vt[((size_t)(b * HH + h) * DHD + dh) * NNN + n] = val;
        else if (mat == 0)  Qb[((size_t)(b * HH + h) * NNN + n) * DHD + dh] = val;
        else                Kb[((size_t)(b * HH + h) * NNN + n) * DHD + dh] = val;
      }
    }
  } else {                                 // ---- Wo transpose ----
    const int idx = bid - 33536;
    const int bx = idx & 7, by = idx >> 3;
    const int c = tid & 31, r8 = tid >> 5;
    #pragma unroll
    for (int i = 0; i < 4; ++i) {
      int r = r8 + i * 8;
      tl[r][c] = Wo[(size_t)(by * 32 + r) * DIN + bx * 32 + c];
    }
    __syncthreads();
    #pragma unroll
    for (int i = 0; i < 4; ++i) {
      int r = r8 + i * 8;
      Wot[(size_t)(bx * 32 + r) * DIN + by * 32 + c] = tl[c][r];
    }
  }
}

// ---------------- fused masked attention ----------------
// block = 4 waves; wave w handles keys [w*512,(w+1)*512) for 32 queries.
// No-max softmax; P exchanged cross-lane via shfl (no LDS/barriers in K-loop);
// block-level O/l reduction in LDS at the end -> normalized AO.
__global__ __launch_bounds__(256) void attn(
    const unsigned short* __restrict__ Qb, const unsigned short* __restrict__ Kb,
    const unsigned short* __restrict__ Vt, const unsigned long long* __restrict__ Mk,
    float* __restrict__ AO) {
  __shared__ float OL[4][32][33];
  __shared__ float LL[4][32];
  const int tid = threadIdx.x;
  const int w = tid >> 6, lane = tid & 63;
  const int qi = lane & 31, hi = lane >> 5;
  const int qt = blockIdx.x, bh = blockIdx.y, b = bh >> 3, h = bh & 7;
  const int q = qt * 32 + qi;
  const int k0 = w * 512;

  const unsigned short* qp = Qb + ((size_t)bh * NNN + q) * DHD + hi * 8;
  const short8 bq0 = *(const short8*)qp;
  const short8 bq1 = *(const short8*)(qp + 16);

  f32x16 accO;
  #pragma unroll
  for (int i = 0; i < 16; ++i) accO[i] = 0.f;
  float lsum = 0.f;

  const unsigned long long* mrow = Mk + ((size_t)b * NNN + q) * NW + w * 8;
  const unsigned short* kbase = Kb + ((size_t)bh * NNN + k0 + qi) * DHD + hi * 8;  // qi = key row
  const unsigned short* vbase = Vt + ((size_t)bh * DHD + qi) * NNN + k0 + hi * 8;  // qi = dh row

  for (int wd = 0; wd < 8; ++wd) {
    unsigned long long mw = mrow[wd];
    #pragma unroll
    for (int half = 0; half < 2; ++half) {
      const int kb = (wd * 2 + half) * 32;
      const unsigned int mq = (unsigned int)(mw >> (half * 32 + hi * 4));

      short8 ak0 = *(const short8*)(kbase + (size_t)kb * DHD);
      short8 ak1 = *(const short8*)(kbase + (size_t)kb * DHD + 16);
      short8 av0 = *(const short8*)(vbase + kb);
      short8 av1 = *(const short8*)(vbase + kb + 16);

      f32x16 z;
      #pragma unroll
      for (int i = 0; i < 16; ++i) z[i] = 0.f;
      // S^T: A=K(m=key), B=Q(n=query); C: query=lane&31, key=(reg&3)+8*(reg>>2)+4*hi
      f32x16 st = __builtin_amdgcn_mfma_f32_32x32x16_bf16(ak0, bq0, z, 0, 0, 0);
      st = __builtin_amdgcn_mfma_f32_32x32x16_bf16(ak1, bq1, st, 0, 0, 0);

      // exp2 then zero masked via sign-extended bit AND (folds to v_bfe_i32+v_and)
      unsigned int pk[4][2];
      #pragma unroll
      for (int g = 0; g < 4; ++g) {
        float pv[4];
        #pragma unroll
        for (int r = 0; r < 4; ++r) {
          float e = EXP2(st[g * 4 + r]);
          int msk = ((int)(mq << (31 - (g * 8 + r)))) >> 31;
          float p = __uint_as_float(__float_as_uint(e) & (unsigned int)msk);
          pv[r] = p;
          lsum += p;
        }
        pk[g][0] = pk2(pv[0], pv[1]);
        pk[g][1] = pk2(pv[2], pv[3]);
      }

      // cross-lane exchange: lane needs partner(hi^1)'s group g=hi (frag1) / 2+hi (frag2)
      unsigned int kA0 = hi ? pk[1][0] : pk[0][0], kA1 = hi ? pk[1][1] : pk[0][1];
      unsigned int tA0 = hi ? pk[0][0] : pk[1][0], tA1 = hi ? pk[0][1] : pk[1][1];
      unsigned int kB0 = hi ? pk[3][0] : pk[2][0], kB1 = hi ? pk[3][1] : pk[2][1];
      unsigned int tB0 = hi ? pk[2][0] : pk[3][0], tB1 = hi ? pk[2][1] : pk[3][1];
      unsigned int xA0 = __shfl_xor((int)tA0, 32, 64), xA1 = __shfl_xor((int)tA1, 32, 64);
      unsigned int xB0 = __shfl_xor((int)tB0, 32, 64), xB1 = __shfl_xor((int)tB1, 32, 64);

      union { short8 s; unsigned int u[4]; } F1, F2;
      F1.u[0] = hi ? xA0 : kA0; F1.u[1] = hi ? xA1 : kA1;
      F1.u[2] = hi ? kA0 : xA0; F1.u[3] = hi ? kA1 : xA1;
      F2.u[0] = hi ? xB0 : kB0; F2.u[1] = hi ? xB1 : kB1;
      F2.u[2] = hi ? kB0 : xB0; F2.u[3] = hi ? kB1 : xB1;

      // O^T += V^T * P^T
      accO = __builtin_amdgcn_mfma_f32_32x32x16_bf16(av0, F1.s, accO, 0, 0, 0);
      accO = __builtin_amdgcn_mfma_f32_32x32x16_bf16(av1, F2.s, accO, 0, 0, 0);
    }
  }

  lsum += __shfl_xor(lsum, 32, 64);   // hi halves cover disjoint keys

  #pragma unroll
  for (int g = 0; g < 4; ++g)
    #pragma unroll
    for (int r = 0; r < 4; ++r)
      OL[w][qi][g * 8 + hi * 4 + r] = accO[g * 4 + r];
  if (hi == 0) LL[w][qi] = lsum;
  __syncthreads();

  const int ql = tid >> 3, c4 = (tid & 7) * 4;
  float l = LL[0][ql] + LL[1][ql] + LL[2][ql] + LL[3][ql];
  float inv = 1.0f / l;
  float4 o;
  o.x = (OL[0][ql][c4 + 0] + OL[1][ql][c4 + 0] + OL[2][ql][c4 + 0] + OL[3][ql][c4 + 0]) * inv;
  o.y = (OL[0][ql][c4 + 1] + OL[1][ql][c4 + 1] + OL[2][ql][c4 + 1] + OL[3][ql][c4 + 1]) * inv;
  o.z = (OL[0][ql][c4 + 2] + OL[1][ql][c4 + 2] + OL[2][ql][c4 + 2] + OL[3][ql][c4 + 2]) * inv;
  o.w = (OL[0][ql][c4 + 3] + OL[1][ql][c4 + 3] + OL[2][ql][c4 + 3] + OL[3][ql][c4 + 3]) * inv;
  *(float4*)(AO + ((size_t)(b * NNN + qt * 32 + ql)) * DIN + h * DHD + c4) = o;
}

// ---------------- output projection + bias (fp32) ----------------
__global__ __launch_bounds__(256) void out_proj(const float* __restrict__ AO,
                                                const float* __restrict__ Wot,
                                                const float* __restrict__ bo,
                                                float* __restrict__ out) {
  const int t = threadIdx.x;
  const int row0 = blockIdx.x * 8;
  float acc[8];
  #pragma unroll
  for (int r = 0; r < 8; ++r) acc[r] = 0.f;

  const float* wp = Wot + t;
  #pragma unroll 2
  for (int k4 = 0; k4 < 64; ++k4) {
    float w0 = wp[(size_t)(k4 * 4 + 0) * DIN];
    float w1 = wp[(size_t)(k4 * 4 + 1) * DIN];
    float w2 = wp[(size_t)(k4 * 4 + 2) * DIN];
    float w3 = wp[(size_t)(k4 * 4 + 3) * DIN];
    #pragma unroll
    for (int r = 0; r < 8; ++r) {
      float4 a = *(const float4*)(AO + (size_t)(row0 + r) * DIN + k4 * 4);
      acc[r] += a.x * w0 + a.y * w1 + a.z * w2 + a.w * w3;
    }
  }
  float bias = bo[t];
  #pragma unroll
  for (int r = 0; r < 8; ++r) out[(size_t)(row0 + r) * DIN + t] = acc[r] + bias;
}

extern "C" void kernel_launch(void* const* d_in, const int* in_sizes, int n_in,
                              void* d_out, int out_size, void* d_ws, size_t ws_size,
                              hipStream_t stream) {
  const float* x   = (const float*)d_in[0];
  const float* adj = (const float*)d_in[1];
  const float* Wq  = (const float*)d_in[2];
  const float* Wk  = (const float*)d_in[3];
  const float* Wv  = (const float*)d_in[4];
  const float* Wo  = (const float*)d_in[5];
  const float* bo  = (const float*)d_in[6];
  float* out = (float*)d_out;

  char* ws = (char*)d_ws;
  unsigned short* Qb = (unsigned short*)(ws);                         // 2 MB
  unsigned short* Kb = (unsigned short*)(ws + (2ull << 20));          // 2 MB
  unsigned short* Vt = (unsigned short*)(ws + (4ull << 20));          // 2 MB
  unsigned long long* Mk = (unsigned long long*)(ws + (6ull << 20));  // 1 MB
  float* Wot = (float*)(ws + (7ull << 20));                           // 256 KB
  float* AO  = (float*)(ws + (8ull << 20));                           // 4 MB

  prep<<<dim3(33600), 256, 0, stream>>>(adj, Mk, x, Wq, Wk, Wv, Qb, Kb, Vt, Wo, Wot);
  attn<<<dim3(NNN / 32, BB * HH), 256, 0, stream>>>(Qb, Kb, Vt, Mk, AO);
  out_proj<<<dim3(BB * NNN / 8), 256, 0, stream>>>(AO, Wot, bo, out);
}

// Round 5
// 167.752 us; speedup vs baseline: 1.2190x; 1.2190x over previous
//
#include <hip/hip_runtime.h>
#include <hip/hip_bf16.h>

#define BB   2
#define NNN  2048
#define DIN  256
#define HH   8
#define DHD  32
#define NW   (NNN/64)   // 32 mask words per row

typedef __attribute__((ext_vector_type(8))) short short8;
typedef __attribute__((ext_vector_type(4))) float f32x4;
typedef __attribute__((ext_vector_type(16))) float f32x16;

#if __has_builtin(__builtin_amdgcn_exp2f)
#define EXP2(x) __builtin_amdgcn_exp2f(x)
#else
#define EXP2(x) exp2f(x)
#endif

__device__ __forceinline__ unsigned int pk2(float a, float b) {
  union { __hip_bfloat162 h2; unsigned int u; } cv;
  cv.h2 = __float22bfloat162_rn(float2{a, b});   // v_cvt_pk_bf16_f32, RNE
  return cv.u;
}
__device__ __forceinline__ unsigned short f2bf(float f) {
  unsigned int u = __float_as_uint(f);
  u += 0x7fffu + ((u >> 16) & 1u);
  return (unsigned short)(u >> 16);
}

#define QSCALE (0.17677669529663687f * 1.4426950408889634f)  // 1/sqrt(32) * log2(e)

// ---------------- fused prep ----------------
// blocks [0,512): adj -> bitmask, 1 thread = 1 u64 word (64 floats, 16 float4 loads: MLP)
// [512,1280): QKV MFMA gemm (inline W cast) | [1280,1344): Wo -> Wo^T
__global__ __launch_bounds__(256) void prep(
    const float* __restrict__ adj, unsigned long long* __restrict__ Mk,
    const float* __restrict__ x, const float* __restrict__ Wq,
    const float* __restrict__ Wk, const float* __restrict__ Wv,
    unsigned short* __restrict__ Qb, unsigned short* __restrict__ Kb,
    unsigned short* __restrict__ Vt,
    const float* __restrict__ Wo, float* __restrict__ Wot) {
  __shared__ float tl[32][33];
  const int bid = blockIdx.x, tid = threadIdx.x;

  if (bid < 512) {                         // ---- adjacency -> 64-bit masks, MLP version ----
    size_t g = (size_t)bid * 256 + tid;    // word index, [0, 131072)
    const float4* ap = (const float4*)(adj + g * 64);
    unsigned long long m = 0;
    #pragma unroll
    for (int j = 0; j < 16; ++j) {
      float4 v = ap[j];
      unsigned long long nib =
          (unsigned long long)(v.x != 0.0f)        |
          ((unsigned long long)(v.y != 0.0f) << 1) |
          ((unsigned long long)(v.z != 0.0f) << 2) |
          ((unsigned long long)(v.w != 0.0f) << 3);
      m |= nib << (4 * j);
    }
    Mk[g] = m;
  } else if (bid < 1280) {                 // ---- QKV projection, 1 wave-task each ----
    const int lane = tid & 63, col = lane & 15, quad = lane >> 4;
    const int task = (bid - 512) * 4 + (tid >> 6);   // 3072 tasks
    const int y = task % 12;
    const int row0 = (task / 12) * 16;
    const int mat = y >> 2, ocb = (y & 3) * 64;
    const float* W = (mat == 0) ? Wq : (mat == 1) ? Wk : Wv;

    f32x4 acc[4];
    #pragma unroll
    for (int c = 0; c < 4; ++c) acc[c] = (f32x4){0.f, 0.f, 0.f, 0.f};

    #pragma unroll
    for (int kk = 0; kk < 8; ++kk) {
      const float* xp = x + (size_t)(row0 + col) * DIN + kk * 32 + quad * 8;
      float4 a0 = *(const float4*)xp, a1 = *(const float4*)(xp + 4);
      union { short8 s; unsigned int u[4]; } af;
      af.u[0] = pk2(a0.x, a0.y); af.u[1] = pk2(a0.z, a0.w);
      af.u[2] = pk2(a1.x, a1.y); af.u[3] = pk2(a1.z, a1.w);
      #pragma unroll
      for (int c = 0; c < 4; ++c) {
        const float* wp = W + (size_t)(ocb + c * 16 + col) * DIN + kk * 32 + quad * 8;
        float4 b0 = *(const float4*)wp, b1 = *(const float4*)(wp + 4);
        union { short8 s; unsigned int u[4]; } bw;
        bw.u[0] = pk2(b0.x, b0.y); bw.u[1] = pk2(b0.z, b0.w);
        bw.u[2] = pk2(b1.x, b1.y); bw.u[3] = pk2(b1.z, b1.w);
        acc[c] = __builtin_amdgcn_mfma_f32_16x16x32_bf16(af.s, bw.s, acc[c], 0, 0, 0);
      }
    }
    const float scale = (mat == 0) ? QSCALE : 1.0f;
    #pragma unroll
    for (int c = 0; c < 4; ++c) {
      int oc = ocb + c * 16 + col, h = oc >> 5, dh = oc & 31;
      #pragma unroll
      for (int r = 0; r < 4; ++r) {
        int row = row0 + quad * 4 + r;
        int b = row >> 11, n = row & (NNN - 1);
        unsigned short val = f2bf(acc[c][r] * scale);
        if (mat == 2)       Vt[((size_t)(b * HH + h) * DHD + dh) * NNN + n] = val;
        else if (mat == 0)  Qb[((size_t)(b * HH + h) * NNN + n) * DHD + dh] = val;
        else                Kb[((size_t)(b * HH + h) * NNN + n) * DHD + dh] = val;
      }
    }
  } else {                                 // ---- Wo transpose ----
    const int idx = bid - 1280;
    const int bx = idx & 7, by = idx >> 3;
    const int c = tid & 31, r8 = tid >> 5;
    #pragma unroll
    for (int i = 0; i < 4; ++i) {
      int r = r8 + i * 8;
      tl[r][c] = Wo[(size_t)(by * 32 + r) * DIN + bx * 32 + c];
    }
    __syncthreads();
    #pragma unroll
    for (int i = 0; i < 4; ++i) {
      int r = r8 + i * 8;
      Wot[(size_t)(bx * 32 + r) * DIN + by * 32 + c] = tl[c][r];
    }
  }
}

// ---------------- fused masked attention ----------------
// block = 4 waves; wave w handles keys [w*512,(w+1)*512) for 32 queries.
// No-max softmax; P exchanged cross-lane via shfl (no LDS/barriers in K-loop);
// block-level O/l reduction in LDS at the end -> normalized AO.
__global__ __launch_bounds__(256) void attn(
    const unsigned short* __restrict__ Qb, const unsigned short* __restrict__ Kb,
    const unsigned short* __restrict__ Vt, const unsigned long long* __restrict__ Mk,
    float* __restrict__ AO) {
  __shared__ float OL[4][32][33];
  __shared__ float LL[4][32];
  const int tid = threadIdx.x;
  const int w = tid >> 6, lane = tid & 63;
  const int qi = lane & 31, hi = lane >> 5;
  const int qt = blockIdx.x, bh = blockIdx.y, b = bh >> 3, h = bh & 7;
  const int q = qt * 32 + qi;
  const int k0 = w * 512;

  const unsigned short* qp = Qb + ((size_t)bh * NNN + q) * DHD + hi * 8;
  const short8 bq0 = *(const short8*)qp;
  const short8 bq1 = *(const short8*)(qp + 16);

  f32x16 accO;
  #pragma unroll
  for (int i = 0; i < 16; ++i) accO[i] = 0.f;
  float lsum = 0.f;

  const unsigned long long* mrow = Mk + ((size_t)b * NNN + q) * NW + w * 8;
  const unsigned short* kbase = Kb + ((size_t)bh * NNN + k0 + qi) * DHD + hi * 8;  // qi = key row
  const unsigned short* vbase = Vt + ((size_t)bh * DHD + qi) * NNN + k0 + hi * 8;  // qi = dh row

  for (int wd = 0; wd < 8; ++wd) {
    unsigned long long mw = mrow[wd];
    #pragma unroll
    for (int half = 0; half < 2; ++half) {
      const int kb = (wd * 2 + half) * 32;
      const unsigned int mq = (unsigned int)(mw >> (half * 32 + hi * 4));

      short8 ak0 = *(const short8*)(kbase + (size_t)kb * DHD);
      short8 ak1 = *(const short8*)(kbase + (size_t)kb * DHD + 16);
      short8 av0 = *(const short8*)(vbase + kb);
      short8 av1 = *(const short8*)(vbase + kb + 16);

      f32x16 z;
      #pragma unroll
      for (int i = 0; i < 16; ++i) z[i] = 0.f;
      // S^T: A=K(m=key), B=Q(n=query); C: query=lane&31, key=(reg&3)+8*(reg>>2)+4*hi
      f32x16 st = __builtin_amdgcn_mfma_f32_32x32x16_bf16(ak0, bq0, z, 0, 0, 0);
      st = __builtin_amdgcn_mfma_f32_32x32x16_bf16(ak1, bq1, st, 0, 0, 0);

      // exp2 then zero masked via sign-extended bit AND
      unsigned int pk[4][2];
      #pragma unroll
      for (int g = 0; g < 4; ++g) {
        float pv[4];
        #pragma unroll
        for (int r = 0; r < 4; ++r) {
          float e = EXP2(st[g * 4 + r]);
          int msk = ((int)(mq << (31 - (g * 8 + r)))) >> 31;
          float p = __uint_as_float(__float_as_uint(e) & (unsigned int)msk);
          pv[r] = p;
          lsum += p;
        }
        pk[g][0] = pk2(pv[0], pv[1]);
        pk[g][1] = pk2(pv[2], pv[3]);
      }

      // cross-lane exchange: lane needs partner(hi^1)'s group g=hi (frag1) / 2+hi (frag2)
      unsigned int kA0 = hi ? pk[1][0] : pk[0][0], kA1 = hi ? pk[1][1] : pk[0][1];
      unsigned int tA0 = hi ? pk[0][0] : pk[1][0], tA1 = hi ? pk[0][1] : pk[1][1];
      unsigned int kB0 = hi ? pk[3][0] : pk[2][0], kB1 = hi ? pk[3][1] : pk[2][1];
      unsigned int tB0 = hi ? pk[2][0] : pk[3][0], tB1 = hi ? pk[2][1] : pk[3][1];
      unsigned int xA0 = __shfl_xor((int)tA0, 32, 64), xA1 = __shfl_xor((int)tA1, 32, 64);
      unsigned int xB0 = __shfl_xor((int)tB0, 32, 64), xB1 = __shfl_xor((int)tB1, 32, 64);

      union { short8 s; unsigned int u[4]; } F1, F2;
      F1.u[0] = hi ? xA0 : kA0; F1.u[1] = hi ? xA1 : kA1;
      F1.u[2] = hi ? kA0 : xA0; F1.u[3] = hi ? kA1 : xA1;
      F2.u[0] = hi ? xB0 : kB0; F2.u[1] = hi ? xB1 : kB1;
      F2.u[2] = hi ? kB0 : xB0; F2.u[3] = hi ? kB1 : xB1;

      // O^T += V^T * P^T
      accO = __builtin_amdgcn_mfma_f32_32x32x16_bf16(av0, F1.s, accO, 0, 0, 0);
      accO = __builtin_amdgcn_mfma_f32_32x32x16_bf16(av1, F2.s, accO, 0, 0, 0);
    }
  }

  lsum += __shfl_xor(lsum, 32, 64);   // hi halves cover disjoint keys

  #pragma unroll
  for (int g = 0; g < 4; ++g)
    #pragma unroll
    for (int r = 0; r < 4; ++r)
      OL[w][qi][g * 8 + hi * 4 + r] = accO[g * 4 + r];
  if (hi == 0) LL[w][qi] = lsum;
  __syncthreads();

  const int ql = tid >> 3, c4 = (tid & 7) * 4;
  float l = LL[0][ql] + LL[1][ql] + LL[2][ql] + LL[3][ql];
  float inv = 1.0f / l;
  float4 o;
  o.x = (OL[0][ql][c4 + 0] + OL[1][ql][c4 + 0] + OL[2][ql][c4 + 0] + OL[3][ql][c4 + 0]) * inv;
  o.y = (OL[0][ql][c4 + 1] + OL[1][ql][c4 + 1] + OL[2][ql][c4 + 1] + OL[3][ql][c4 + 1]) * inv;
  o.z = (OL[0][ql][c4 + 2] + OL[1][ql][c4 + 2] + OL[2][ql][c4 + 2] + OL[3][ql][c4 + 2]) * inv;
  o.w = (OL[0][ql][c4 + 3] + OL[1][ql][c4 + 3] + OL[2][ql][c4 + 3] + OL[3][ql][c4 + 3]) * inv;
  *(float4*)(AO + ((size_t)(b * NNN + qt * 32 + ql)) * DIN + h * DHD + c4) = o;
}

// ---------------- output projection + bias (fp32) ----------------
__global__ __launch_bounds__(256) void out_proj(const float* __restrict__ AO,
                                                const float* __restrict__ Wot,
                                                const float* __restrict__ bo,
                                                float* __restrict__ out) {
  const int t = threadIdx.x;
  const int row0 = blockIdx.x * 8;
  float acc[8];
  #pragma unroll
  for (int r = 0; r < 8; ++r) acc[r] = 0.f;

  const float* wp = Wot + t;
  #pragma unroll 2
  for (int k4 = 0; k4 < 64; ++k4) {
    float w0 = wp[(size_t)(k4 * 4 + 0) * DIN];
    float w1 = wp[(size_t)(k4 * 4 + 1) * DIN];
    float w2 = wp[(size_t)(k4 * 4 + 2) * DIN];
    float w3 = wp[(size_t)(k4 * 4 + 3) * DIN];
    #pragma unroll
    for (int r = 0; r < 8; ++r) {
      float4 a = *(const float4*)(AO + (size_t)(row0 + r) * DIN + k4 * 4);
      acc[r] += a.x * w0 + a.y * w1 + a.z * w2 + a.w * w3;
    }
  }
  float bias = bo[t];
  #pragma unroll
  for (int r = 0; r < 8; ++r) out[(size_t)(row0 + r) * DIN + t] = acc[r] + bias;
}

extern "C" void kernel_launch(void* const* d_in, const int* in_sizes, int n_in,
                              void* d_out, int out_size, void* d_ws, size_t ws_size,
                              hipStream_t stream) {
  const float* x   = (const float*)d_in[0];
  const float* adj = (const float*)d_in[1];
  const float* Wq  = (const float*)d_in[2];
  const float* Wk  = (const float*)d_in[3];
  const float* Wv  = (const float*)d_in[4];
  const float* Wo  = (const float*)d_in[5];
  const float* bo  = (const float*)d_in[6];
  float* out = (float*)d_out;

  char* ws = (char*)d_ws;
  unsigned short* Qb = (unsigned short*)(ws);                         // 2 MB
  unsigned short* Kb = (unsigned short*)(ws + (2ull << 20));          // 2 MB
  unsigned short* Vt = (unsigned short*)(ws + (4ull << 20));          // 2 MB
  unsigned long long* Mk = (unsigned long long*)(ws + (6ull << 20));  // 1 MB
  float* Wot = (float*)(ws + (7ull << 20));                           // 256 KB
  float* AO  = (float*)(ws + (8ull << 20));                           // 4 MB

  prep<<<dim3(1344), 256, 0, stream>>>(adj, Mk, x, Wq, Wk, Wv, Qb, Kb, Vt, Wo, Wot);
  attn<<<dim3(NNN / 32, BB * HH), 256, 0, stream>>>(Qb, Kb, Vt, Mk, AO);
  out_proj<<<dim3(BB * NNN / 8), 256, 0, stream>>>(AO, Wot, bo, out);
}

// Round 6
// 161.475 us; speedup vs baseline: 1.2664x; 1.0389x over previous
//
#include <hip/hip_runtime.h>
#include <hip/hip_bf16.h>

#define BB   2
#define NNN  2048
#define DIN  256
#define HH   8
#define DHD  32
#define NW   32   // u64 mask words per row (8 groups x 4 ballot words)

typedef __attribute__((ext_vector_type(8))) short short8;
typedef __attribute__((ext_vector_type(4))) float f32x4;
typedef __attribute__((ext_vector_type(16))) float f32x16;

#if __has_builtin(__builtin_amdgcn_exp2f)
#define EXP2(x) __builtin_amdgcn_exp2f(x)
#else
#define EXP2(x) exp2f(x)
#endif

__device__ __forceinline__ unsigned int pk2(float a, float b) {
  union { __hip_bfloat162 h2; unsigned int u; } cv;
  cv.h2 = __float22bfloat162_rn(float2{a, b});   // v_cvt_pk_bf16_f32, RNE
  return cv.u;
}
__device__ __forceinline__ unsigned short f2bf(float f) {
  unsigned int u = __float_as_uint(f);
  u += 0x7fffu + ((u >> 16) & 1u);
  return (unsigned short)(u >> 16);
}

#define QSCALE (0.17677669529663687f * 1.4426950408889634f)  // 1/sqrt(32) * log2(e)

// ---------------- fused prep ----------------
// [0,1024): adj -> ballot masks (coalesced; 1 wave = 1 adj row)
//   layout: Mk[(row*8 + G)*4 + c], bit L of word c = adj[row][G*256 + 4L + c]
// [1024,1792): QKV MFMA gemm (inline W cast)
// [1792,1856): Wo fp32 -> bf16
__global__ __launch_bounds__(256) void prep(
    const float* __restrict__ adj, unsigned long long* __restrict__ Mk,
    const float* __restrict__ x, const float* __restrict__ Wq,
    const float* __restrict__ Wk, const float* __restrict__ Wv,
    unsigned short* __restrict__ Qb, unsigned short* __restrict__ Kb,
    unsigned short* __restrict__ Vt,
    const float* __restrict__ Wo, unsigned short* __restrict__ Wob) {
  const int bid = blockIdx.x, tid = threadIdx.x;

  if (bid < 1024) {                        // ---- masks: 4096 rows, 1 wave each ----
    const int lane = tid & 63;
    const int row = bid * 4 + (tid >> 6);
    const float* rp = adj + (size_t)row * NNN + lane * 4;
    #pragma unroll
    for (int o = 0; o < 2; ++o) {
      float4 vv[4];
      #pragma unroll
      for (int g = 0; g < 4; ++g)
        vv[g] = *(const float4*)(rp + (o * 4 + g) * 256);
      #pragma unroll
      for (int g = 0; g < 4; ++g) {
        unsigned long long b0 = __ballot(vv[g].x != 0.0f);
        unsigned long long b1 = __ballot(vv[g].y != 0.0f);
        unsigned long long b2 = __ballot(vv[g].z != 0.0f);
        unsigned long long b3 = __ballot(vv[g].w != 0.0f);
        if (lane < 4) {
          unsigned long long bs = (lane == 0) ? b0 : (lane == 1) ? b1 : (lane == 2) ? b2 : b3;
          Mk[(size_t)row * NW + (o * 4 + g) * 4 + lane] = bs;
        }
      }
    }
  } else if (bid < 1792) {                 // ---- QKV projection, 1 wave-task each ----
    const int lane = tid & 63, col = lane & 15, quad = lane >> 4;
    const int task = (bid - 1024) * 4 + (tid >> 6);   // 3072 tasks
    const int y = task % 12;
    const int row0 = (task / 12) * 16;
    const int mat = y >> 2, ocb = (y & 3) * 64;
    const float* W = (mat == 0) ? Wq : (mat == 1) ? Wk : Wv;

    f32x4 acc[4];
    #pragma unroll
    for (int c = 0; c < 4; ++c) acc[c] = (f32x4){0.f, 0.f, 0.f, 0.f};

    #pragma unroll
    for (int kk = 0; kk < 8; ++kk) {
      const float* xp = x + (size_t)(row0 + col) * DIN + kk * 32 + quad * 8;
      float4 a0 = *(const float4*)xp, a1 = *(const float4*)(xp + 4);
      union { short8 s; unsigned int u[4]; } af;
      af.u[0] = pk2(a0.x, a0.y); af.u[1] = pk2(a0.z, a0.w);
      af.u[2] = pk2(a1.x, a1.y); af.u[3] = pk2(a1.z, a1.w);
      #pragma unroll
      for (int c = 0; c < 4; ++c) {
        const float* wp = W + (size_t)(ocb + c * 16 + col) * DIN + kk * 32 + quad * 8;
        float4 b0 = *(const float4*)wp, b1 = *(const float4*)(wp + 4);
        union { short8 s; unsigned int u[4]; } bw;
        bw.u[0] = pk2(b0.x, b0.y); bw.u[1] = pk2(b0.z, b0.w);
        bw.u[2] = pk2(b1.x, b1.y); bw.u[3] = pk2(b1.z, b1.w);
        acc[c] = __builtin_amdgcn_mfma_f32_16x16x32_bf16(af.s, bw.s, acc[c], 0, 0, 0);
      }
    }
    const float scale = (mat == 0) ? QSCALE : 1.0f;
    #pragma unroll
    for (int c = 0; c < 4; ++c) {
      int oc = ocb + c * 16 + col, h = oc >> 5, dh = oc & 31;
      #pragma unroll
      for (int r = 0; r < 4; ++r) {
        int row = row0 + quad * 4 + r;
        int b = row >> 11, n = row & (NNN - 1);
        unsigned short val = f2bf(acc[c][r] * scale);
        if (mat == 2)       Vt[((size_t)(b * HH + h) * DHD + dh) * NNN + n] = val;
        else if (mat == 0)  Qb[((size_t)(b * HH + h) * NNN + n) * DHD + dh] = val;
        else                Kb[((size_t)(b * HH + h) * NNN + n) * DHD + dh] = val;
      }
    }
  } else {                                 // ---- Wo -> bf16 ----
    int i = (bid - 1792) * 1024 + tid * 4;
    float4 v = *(const float4*)(Wo + i);
    unsigned int p[2] = {pk2(v.x, v.y), pk2(v.z, v.w)};
    *(uint2*)(Wob + i) = *(const uint2*)p;
  }
}

// ---------------- fused masked attention ----------------
// block = 4 waves; wave w handles keys [w*512,(w+1)*512) for 32 queries.
// XCD-swizzled grid: all q-tiles of a (b,h) pair stay on one XCD (K/V L2-resident).
// No-max softmax; ballot-layout masks; P exchanged via shfl; AO written bf16.
__global__ __launch_bounds__(256) void attn(
    const unsigned short* __restrict__ Qb, const unsigned short* __restrict__ Kb,
    const unsigned short* __restrict__ Vt, const unsigned long long* __restrict__ Mk,
    unsigned short* __restrict__ AOb) {
  __shared__ float OL[4][32][33];
  __shared__ float LL[4][32];
  const int tid = threadIdx.x;
  const int w = tid >> 6, lane = tid & 63;
  const int qi = lane & 31, hi = lane >> 5;
  const int bid = blockIdx.x;
  const int xcd = bid & 7, j = bid >> 3;
  const int bh = xcd * 2 + (j >> 6);       // 2 bh per XCD
  const int qt = j & 63;
  const int b = bh >> 3, h = bh & 7;
  const int q = qt * 32 + qi;
  const int k0 = w * 512;

  const unsigned short* qp = Qb + ((size_t)bh * NNN + q) * DHD + hi * 8;
  const short8 bq0 = *(const short8*)qp;
  const short8 bq1 = *(const short8*)(qp + 16);

  f32x16 accO;
  #pragma unroll
  for (int i = 0; i < 16; ++i) accO[i] = 0.f;
  float lsum = 0.f;

  const unsigned long long* mrow = Mk + ((size_t)b * NNN + q) * NW + w * 8;  // 2 groups x 4 words
  const unsigned short* kbase = Kb + ((size_t)bh * NNN + k0 + qi) * DHD + hi * 8;  // qi = key row
  const unsigned short* vbase = Vt + ((size_t)bh * DHD + qi) * NNN + k0 + hi * 8;  // qi = dh row

  #pragma unroll
  for (int G2 = 0; G2 < 2; ++G2) {
    unsigned long long bm[4];
    #pragma unroll
    for (int c = 0; c < 4; ++c) bm[c] = mrow[G2 * 4 + c];

    #pragma unroll
    for (int sub = 0; sub < 8; ++sub) {
      const int kb = G2 * 256 + sub * 32;
      // byte `sub` of bm[r] holds bits (g*2+hi) for keys kb + g*8 + hi*4 + r
      unsigned int mb[4];
      #pragma unroll
      for (int c = 0; c < 4; ++c) mb[c] = (unsigned int)(bm[c] >> (sub * 8)) & 0xffu;

      short8 ak0 = *(const short8*)(kbase + (size_t)kb * DHD);
      short8 ak1 = *(const short8*)(kbase + (size_t)kb * DHD + 16);
      short8 av0 = *(const short8*)(vbase + kb);
      short8 av1 = *(const short8*)(vbase + kb + 16);

      f32x16 z;
      #pragma unroll
      for (int i = 0; i < 16; ++i) z[i] = 0.f;
      // S^T: A=K(m=key), B=Q(n=query); C: query=lane&31, key=(reg&3)+8*(reg>>2)+4*hi
      f32x16 st = __builtin_amdgcn_mfma_f32_32x32x16_bf16(ak0, bq0, z, 0, 0, 0);
      st = __builtin_amdgcn_mfma_f32_32x32x16_bf16(ak1, bq1, st, 0, 0, 0);

      unsigned int pk[4][2];
      #pragma unroll
      for (int g = 0; g < 4; ++g) {
        float pv[4];
        #pragma unroll
        for (int r = 0; r < 4; ++r) {
          float e = EXP2(st[g * 4 + r]);
          int msk = ((int)(mb[r] << (31 - (g * 2 + hi)))) >> 31;
          float p = __uint_as_float(__float_as_uint(e) & (unsigned int)msk);
          pv[r] = p;
          lsum += p;
        }
        pk[g][0] = pk2(pv[0], pv[1]);
        pk[g][1] = pk2(pv[2], pv[3]);
      }

      // cross-lane exchange: lane needs partner(hi^1)'s group g=hi (frag1) / 2+hi (frag2)
      unsigned int kA0 = hi ? pk[1][0] : pk[0][0], kA1 = hi ? pk[1][1] : pk[0][1];
      unsigned int tA0 = hi ? pk[0][0] : pk[1][0], tA1 = hi ? pk[0][1] : pk[1][1];
      unsigned int kB0 = hi ? pk[3][0] : pk[2][0], kB1 = hi ? pk[3][1] : pk[2][1];
      unsigned int tB0 = hi ? pk[2][0] : pk[3][0], tB1 = hi ? pk[2][1] : pk[3][1];
      unsigned int xA0 = __shfl_xor((int)tA0, 32, 64), xA1 = __shfl_xor((int)tA1, 32, 64);
      unsigned int xB0 = __shfl_xor((int)tB0, 32, 64), xB1 = __shfl_xor((int)tB1, 32, 64);

      union { short8 s; unsigned int u[4]; } F1, F2;
      F1.u[0] = hi ? xA0 : kA0; F1.u[1] = hi ? xA1 : kA1;
      F1.u[2] = hi ? kA0 : xA0; F1.u[3] = hi ? kA1 : xA1;
      F2.u[0] = hi ? xB0 : kB0; F2.u[1] = hi ? xB1 : kB1;
      F2.u[2] = hi ? kB0 : xB0; F2.u[3] = hi ? kB1 : xB1;

      // O^T += V^T * P^T
      accO = __builtin_amdgcn_mfma_f32_32x32x16_bf16(av0, F1.s, accO, 0, 0, 0);
      accO = __builtin_amdgcn_mfma_f32_32x32x16_bf16(av1, F2.s, accO, 0, 0, 0);
    }
  }

  lsum += __shfl_xor(lsum, 32, 64);   // hi halves cover disjoint keys

  #pragma unroll
  for (int g = 0; g < 4; ++g)
    #pragma unroll
    for (int r = 0; r < 4; ++r)
      OL[w][qi][g * 8 + hi * 4 + r] = accO[g * 4 + r];
  if (hi == 0) LL[w][qi] = lsum;
  __syncthreads();

  const int ql = tid >> 3, c4 = (tid & 7) * 4;
  float l = LL[0][ql] + LL[1][ql] + LL[2][ql] + LL[3][ql];
  float inv = 1.0f / l;
  float o0 = (OL[0][ql][c4 + 0] + OL[1][ql][c4 + 0] + OL[2][ql][c4 + 0] + OL[3][ql][c4 + 0]) * inv;
  float o1 = (OL[0][ql][c4 + 1] + OL[1][ql][c4 + 1] + OL[2][ql][c4 + 1] + OL[3][ql][c4 + 1]) * inv;
  float o2 = (OL[0][ql][c4 + 2] + OL[1][ql][c4 + 2] + OL[2][ql][c4 + 2] + OL[3][ql][c4 + 2]) * inv;
  float o3 = (OL[0][ql][c4 + 3] + OL[1][ql][c4 + 3] + OL[2][ql][c4 + 3] + OL[3][ql][c4 + 3]) * inv;
  unsigned int pk01 = pk2(o0, o1), pk23 = pk2(o2, o3);
  unsigned int pr[2] = {pk01, pk23};
  *(uint2*)(AOb + ((size_t)(b * NNN + qt * 32 + ql)) * DIN + h * DHD + c4) = *(const uint2*)pr;
}

// ---------------- output projection + bias via bf16 MFMA ----------------
// 1 wave-task = 16 rows x 64 out-cols; 256 blocks x 4 waves
__global__ __launch_bounds__(256) void out_proj(const unsigned short* __restrict__ AOb,
                                                const unsigned short* __restrict__ Wob,
                                                const float* __restrict__ bo,
                                                float* __restrict__ out) {
  const int tid = threadIdx.x;
  const int lane = tid & 63, col = lane & 15, quad = lane >> 4;
  const int task = blockIdx.x * 4 + (tid >> 6);    // 1024 tasks
  const int row0 = (task >> 2) * 16;
  const int ocb = (task & 3) * 64;

  f32x4 acc[4];
  #pragma unroll
  for (int c = 0; c < 4; ++c) acc[c] = (f32x4){0.f, 0.f, 0.f, 0.f};

  #pragma unroll
  for (int kk = 0; kk < 8; ++kk) {
    short8 af = *(const short8*)(AOb + (size_t)(row0 + col) * DIN + kk * 32 + quad * 8);
    #pragma unroll
    for (int c = 0; c < 4; ++c) {
      short8 bw = *(const short8*)(Wob + (size_t)(ocb + c * 16 + col) * DIN + kk * 32 + quad * 8);
      acc[c] = __builtin_amdgcn_mfma_f32_16x16x32_bf16(af, bw, acc[c], 0, 0, 0);
    }
  }
  #pragma unroll
  for (int c = 0; c < 4; ++c) {
    int oc = ocb + c * 16 + col;
    float bias = bo[oc];
    #pragma unroll
    for (int r = 0; r < 4; ++r)
      out[(size_t)(row0 + quad * 4 + r) * DIN + oc] = acc[c][r] + bias;
  }
}

extern "C" void kernel_launch(void* const* d_in, const int* in_sizes, int n_in,
                              void* d_out, int out_size, void* d_ws, size_t ws_size,
                              hipStream_t stream) {
  const float* x   = (const float*)d_in[0];
  const float* adj = (const float*)d_in[1];
  const float* Wq  = (const float*)d_in[2];
  const float* Wk  = (const float*)d_in[3];
  const float* Wv  = (const float*)d_in[4];
  const float* Wo  = (const float*)d_in[5];
  const float* bo  = (const float*)d_in[6];
  float* out = (float*)d_out;

  char* ws = (char*)d_ws;
  unsigned short* Qb  = (unsigned short*)(ws);                         // 2 MB
  unsigned short* Kb  = (unsigned short*)(ws + (2ull << 20));          // 2 MB
  unsigned short* Vt  = (unsigned short*)(ws + (4ull << 20));          // 2 MB
  unsigned long long* Mk = (unsigned long long*)(ws + (6ull << 20));   // 1 MB
  unsigned short* Wob = (unsigned short*)(ws + (7ull << 20));          // 128 KB
  unsigned short* AOb = (unsigned short*)(ws + (8ull << 20));          // 2 MB

  prep<<<dim3(1856), 256, 0, stream>>>(adj, Mk, x, Wq, Wk, Wv, Qb, Kb, Vt, Wo, Wob);
  attn<<<dim3(1024), 256, 0, stream>>>(Qb, Kb, Vt, Mk, AOb);
  out_proj<<<dim3(256), 256, 0, stream>>>(AOb, Wob, bo, out);
}

// Round 7
// 146.921 us; speedup vs baseline: 1.3918x; 1.0991x over previous
//
#include <hip/hip_runtime.h>
#include <hip/hip_bf16.h>

#define BB   2
#define NNN  2048
#define DIN  256
#define HH   8
#define DHD  32
#define NW   32   // u64 mask words per row (8 groups x 4 ballot words)

typedef __attribute__((ext_vector_type(8))) short short8;
typedef __attribute__((ext_vector_type(4))) float f32x4;
typedef __attribute__((ext_vector_type(16))) float f32x16;

#if __has_builtin(__builtin_amdgcn_exp2f)
#define EXP2(x) __builtin_amdgcn_exp2f(x)
#else
#define EXP2(x) exp2f(x)
#endif

__device__ __forceinline__ unsigned int pk2(float a, float b) {
  union { __hip_bfloat162 h2; unsigned int u; } cv;
  cv.h2 = __float22bfloat162_rn(float2{a, b});   // v_cvt_pk_bf16_f32, RNE
  return cv.u;
}
__device__ __forceinline__ unsigned short f2bf(float f) {
  unsigned int u = __float_as_uint(f);
  u += 0x7fffu + ((u >> 16) & 1u);
  return (unsigned short)(u >> 16);
}

#define QSCALE (0.17677669529663687f * 1.4426950408889634f)  // 1/sqrt(32) * log2(e)

// ---------------- K0: adj -> ballot masks  +  Wo cast ----------------
// [0,1024): masks, 1 wave = 1 adj row (coalesced).
//   layout: Mk[(row*8 + G)*4 + c], bit L of word c = adj[row][G*256 + 4L + c]
// [1024,1088): Wo fp32 -> bf16
__global__ __launch_bounds__(256) void build_mask(
    const float* __restrict__ adj, unsigned long long* __restrict__ Mk,
    const float* __restrict__ Wo, unsigned short* __restrict__ Wob) {
  const int bid = blockIdx.x, tid = threadIdx.x;
  if (bid < 1024) {
    const int lane = tid & 63;
    const int row = bid * 4 + (tid >> 6);
    const float* rp = adj + (size_t)row * NNN + lane * 4;
    #pragma unroll
    for (int o = 0; o < 2; ++o) {
      float4 vv[4];
      #pragma unroll
      for (int g = 0; g < 4; ++g)
        vv[g] = *(const float4*)(rp + (o * 4 + g) * 256);
      #pragma unroll
      for (int g = 0; g < 4; ++g) {
        unsigned long long b0 = __ballot(vv[g].x != 0.0f);
        unsigned long long b1 = __ballot(vv[g].y != 0.0f);
        unsigned long long b2 = __ballot(vv[g].z != 0.0f);
        unsigned long long b3 = __ballot(vv[g].w != 0.0f);
        if (lane < 4) {
          unsigned long long bs = (lane == 0) ? b0 : (lane == 1) ? b1 : (lane == 2) ? b2 : b3;
          Mk[(size_t)row * NW + (o * 4 + g) * 4 + lane] = bs;
        }
      }
    }
  } else {
    int i = (bid - 1024) * 1024 + tid * 4;
    float4 v = *(const float4*)(Wo + i);
    unsigned int p[2] = {pk2(v.x, v.y), pk2(v.z, v.w)};
    *(uint2*)(Wob + i) = *(const uint2*)p;
  }
}

// ---------------- K1: QKV projection, W staged in LDS ----------------
// grid 768: y = bid>>6 (0..11: mat*4 + out-col-block), rb = bid&63 (64-row group).
// Block stages its 64x256 W tile as bf16 in LDS; 4 waves consume (16 rows each).
__global__ __launch_bounds__(256) void qkv_gemm(
    const float* __restrict__ x, const float* __restrict__ Wq,
    const float* __restrict__ Wk, const float* __restrict__ Wv,
    unsigned short* __restrict__ Qb, unsigned short* __restrict__ Kb,
    unsigned short* __restrict__ Vt) {
  __shared__ __align__(16) unsigned short Wl[64][264];   // pad: 528B row stride
  const int tid = threadIdx.x;
  const int y = blockIdx.x >> 6, rb = blockIdx.x & 63;
  const int mat = y >> 2, ocb = (y & 3) * 64;
  const float* Wsrc = ((mat == 0) ? Wq : (mat == 1) ? Wk : Wv) + (size_t)ocb * DIN;

  #pragma unroll
  for (int it = 0; it < 16; ++it) {
    int f4 = it * 256 + tid;
    int oc = f4 >> 6, k4 = f4 & 63;
    float4 v = *(const float4*)(Wsrc + (size_t)oc * DIN + k4 * 4);
    unsigned int p[2] = {pk2(v.x, v.y), pk2(v.z, v.w)};
    *(uint2*)&Wl[oc][k4 * 4] = *(const uint2*)p;
  }
  __syncthreads();

  const int w = tid >> 6, lane = tid & 63, col = lane & 15, quad = lane >> 4;
  const int row0 = rb * 64 + w * 16;

  f32x4 acc[4];
  #pragma unroll
  for (int c = 0; c < 4; ++c) acc[c] = (f32x4){0.f, 0.f, 0.f, 0.f};

  #pragma unroll
  for (int kk = 0; kk < 8; ++kk) {
    const float* xp = x + (size_t)(row0 + col) * DIN + kk * 32 + quad * 8;
    float4 a0 = *(const float4*)xp, a1 = *(const float4*)(xp + 4);
    union { short8 s; unsigned int u[4]; } af;
    af.u[0] = pk2(a0.x, a0.y); af.u[1] = pk2(a0.z, a0.w);
    af.u[2] = pk2(a1.x, a1.y); af.u[3] = pk2(a1.z, a1.w);
    #pragma unroll
    for (int c = 0; c < 4; ++c) {
      short8 bw = *(const short8*)&Wl[c * 16 + col][kk * 32 + quad * 8];
      acc[c] = __builtin_amdgcn_mfma_f32_16x16x32_bf16(af.s, bw, acc[c], 0, 0, 0);
    }
  }
  const float scale = (mat == 0) ? QSCALE : 1.0f;
  #pragma unroll
  for (int c = 0; c < 4; ++c) {
    int oc = ocb + c * 16 + col, h = oc >> 5, dh = oc & 31;
    #pragma unroll
    for (int r = 0; r < 4; ++r) {
      int row = row0 + quad * 4 + r;
      int b = row >> 11, n = row & (NNN - 1);
      unsigned short val = f2bf(acc[c][r] * scale);
      if (mat == 2)       Vt[((size_t)(b * HH + h) * DHD + dh) * NNN + n] = val;
      else if (mat == 0)  Qb[((size_t)(b * HH + h) * NNN + n) * DHD + dh] = val;
      else                Kb[((size_t)(b * HH + h) * NNN + n) * DHD + dh] = val;
    }
  }
}

// ---------------- K2: fused masked attention ----------------
// 512-thread blocks (8 waves); wave w handles keys [w*256,(w+1)*256) for 32 queries.
// XCD-swizzled grid; no-max softmax; ballot masks; P exchanged via shfl;
// block-end LDS combine over 8 waves -> normalized bf16 AO.
__global__ __launch_bounds__(512, 6) void attn(
    const unsigned short* __restrict__ Qb, const unsigned short* __restrict__ Kb,
    const unsigned short* __restrict__ Vt, const unsigned long long* __restrict__ Mk,
    unsigned short* __restrict__ AOb) {
  __shared__ float OL[8][32][33];
  __shared__ float LL[8][32];
  const int tid = threadIdx.x;
  const int w = tid >> 6, lane = tid & 63;
  const int qi = lane & 31, hi = lane >> 5;
  const int bid = blockIdx.x;
  const int xcd = bid & 7, j = bid >> 3;
  const int bh = xcd * 2 + (j >> 6);       // 2 bh per XCD
  const int qt = j & 63;
  const int b = bh >> 3, h = bh & 7;
  const int q = qt * 32 + qi;
  const int k0 = w * 256;

  const unsigned short* qp = Qb + ((size_t)bh * NNN + q) * DHD + hi * 8;
  const short8 bq0 = *(const short8*)qp;
  const short8 bq1 = *(const short8*)(qp + 16);

  f32x16 accO;
  #pragma unroll
  for (int i = 0; i < 16; ++i) accO[i] = 0.f;
  float lsum = 0.f;

  // this wave's 256-key mask group: 4 u64 words
  const unsigned long long* mrow = Mk + ((size_t)b * NNN + q) * NW + w * 4;
  unsigned long long bm[4];
  #pragma unroll
  for (int c = 0; c < 4; ++c) bm[c] = mrow[c];

  const unsigned short* kbase = Kb + ((size_t)bh * NNN + k0 + qi) * DHD + hi * 8;  // qi = key row
  const unsigned short* vbase = Vt + ((size_t)bh * DHD + qi) * NNN + k0 + hi * 8;  // qi = dh row

  #pragma unroll 2
  for (int sub = 0; sub < 8; ++sub) {
    const int kb = sub * 32;
    unsigned int mb[4];
    #pragma unroll
    for (int c = 0; c < 4; ++c) mb[c] = (unsigned int)(bm[c] >> (sub * 8)) & 0xffu;

    short8 ak0 = *(const short8*)(kbase + (size_t)kb * DHD);
    short8 ak1 = *(const short8*)(kbase + (size_t)kb * DHD + 16);
    short8 av0 = *(const short8*)(vbase + kb);
    short8 av1 = *(const short8*)(vbase + kb + 16);

    f32x16 z;
    #pragma unroll
    for (int i = 0; i < 16; ++i) z[i] = 0.f;
    // S^T: A=K(m=key), B=Q(n=query); C: query=lane&31, key=(reg&3)+8*(reg>>2)+4*hi
    f32x16 st = __builtin_amdgcn_mfma_f32_32x32x16_bf16(ak0, bq0, z, 0, 0, 0);
    st = __builtin_amdgcn_mfma_f32_32x32x16_bf16(ak1, bq1, st, 0, 0, 0);

    unsigned int pk[4][2];
    #pragma unroll
    for (int g = 0; g < 4; ++g) {
      float pv[4];
      #pragma unroll
      for (int r = 0; r < 4; ++r) {
        float e = EXP2(st[g * 4 + r]);
        int msk = ((int)(mb[r] << (31 - (g * 2 + hi)))) >> 31;
        float p = __uint_as_float(__float_as_uint(e) & (unsigned int)msk);
        pv[r] = p;
        lsum += p;
      }
      pk[g][0] = pk2(pv[0], pv[1]);
      pk[g][1] = pk2(pv[2], pv[3]);
    }

    // cross-lane exchange: lane needs partner(hi^1)'s group g=hi (frag1) / 2+hi (frag2)
    unsigned int kA0 = hi ? pk[1][0] : pk[0][0], kA1 = hi ? pk[1][1] : pk[0][1];
    unsigned int tA0 = hi ? pk[0][0] : pk[1][0], tA1 = hi ? pk[0][1] : pk[1][1];
    unsigned int kB0 = hi ? pk[3][0] : pk[2][0], kB1 = hi ? pk[3][1] : pk[2][1];
    unsigned int tB0 = hi ? pk[2][0] : pk[3][0], tB1 = hi ? pk[2][1] : pk[3][1];
    unsigned int xA0 = __shfl_xor((int)tA0, 32, 64), xA1 = __shfl_xor((int)tA1, 32, 64);
    unsigned int xB0 = __shfl_xor((int)tB0, 32, 64), xB1 = __shfl_xor((int)tB1, 32, 64);

    union { short8 s; unsigned int u[4]; } F1, F2;
    F1.u[0] = hi ? xA0 : kA0; F1.u[1] = hi ? xA1 : kA1;
    F1.u[2] = hi ? kA0 : xA0; F1.u[3] = hi ? kA1 : xA1;
    F2.u[0] = hi ? xB0 : kB0; F2.u[1] = hi ? xB1 : kB1;
    F2.u[2] = hi ? kB0 : xB0; F2.u[3] = hi ? kB1 : xB1;

    // O^T += V^T * P^T
    accO = __builtin_amdgcn_mfma_f32_32x32x16_bf16(av0, F1.s, accO, 0, 0, 0);
    accO = __builtin_amdgcn_mfma_f32_32x32x16_bf16(av1, F2.s, accO, 0, 0, 0);
  }

  lsum += __shfl_xor(lsum, 32, 64);   // hi halves cover disjoint keys

  #pragma unroll
  for (int g = 0; g < 4; ++g)
    #pragma unroll
    for (int r = 0; r < 4; ++r)
      OL[w][qi][g * 8 + hi * 4 + r] = accO[g * 4 + r];
  if (hi == 0) LL[w][qi] = lsum;
  __syncthreads();

  // 512 threads: 16 threads per query, 2 dh each
  const int ql = tid >> 4, c2 = (tid & 15) * 2;
  float l = 0.f, o0 = 0.f, o1 = 0.f;
  #pragma unroll
  for (int ww = 0; ww < 8; ++ww) {
    l  += LL[ww][ql];
    o0 += OL[ww][ql][c2];
    o1 += OL[ww][ql][c2 + 1];
  }
  float inv = 1.0f / l;
  unsigned int pr = pk2(o0 * inv, o1 * inv);
  *(unsigned int*)(AOb + ((size_t)(b * NNN + qt * 32 + ql)) * DIN + h * DHD + c2) = pr;
}

// ---------------- K3: output projection + bias via bf16 MFMA ----------------
__global__ __launch_bounds__(256) void out_proj(const unsigned short* __restrict__ AOb,
                                                const unsigned short* __restrict__ Wob,
                                                const float* __restrict__ bo,
                                                float* __restrict__ out) {
  const int tid = threadIdx.x;
  const int lane = tid & 63, col = lane & 15, quad = lane >> 4;
  const int task = blockIdx.x * 4 + (tid >> 6);    // 1024 tasks
  const int row0 = (task >> 2) * 16;
  const int ocb = (task & 3) * 64;

  f32x4 acc[4];
  #pragma unroll
  for (int c = 0; c < 4; ++c) acc[c] = (f32x4){0.f, 0.f, 0.f, 0.f};

  #pragma unroll
  for (int kk = 0; kk < 8; ++kk) {
    short8 af = *(const short8*)(AOb + (size_t)(row0 + col) * DIN + kk * 32 + quad * 8);
    #pragma unroll
    for (int c = 0; c < 4; ++c) {
      short8 bw = *(const short8*)(Wob + (size_t)(ocb + c * 16 + col) * DIN + kk * 32 + quad * 8);
      acc[c] = __builtin_amdgcn_mfma_f32_16x16x32_bf16(af, bw, acc[c], 0, 0, 0);
    }
  }
  #pragma unroll
  for (int c = 0; c < 4; ++c) {
    int oc = ocb + c * 16 + col;
    float bias = bo[oc];
    #pragma unroll
    for (int r = 0; r < 4; ++r)
      out[(size_t)(row0 + quad * 4 + r) * DIN + oc] = acc[c][r] + bias;
  }
}

extern "C" void kernel_launch(void* const* d_in, const int* in_sizes, int n_in,
                              void* d_out, int out_size, void* d_ws, size_t ws_size,
                              hipStream_t stream) {
  const float* x   = (const float*)d_in[0];
  const float* adj = (const float*)d_in[1];
  const float* Wq  = (const float*)d_in[2];
  const float* Wk  = (const float*)d_in[3];
  const float* Wv  = (const float*)d_in[4];
  const float* Wo  = (const float*)d_in[5];
  const float* bo  = (const float*)d_in[6];
  float* out = (float*)d_out;

  char* ws = (char*)d_ws;
  unsigned short* Qb  = (unsigned short*)(ws);                         // 2 MB
  unsigned short* Kb  = (unsigned short*)(ws + (2ull << 20));          // 2 MB
  unsigned short* Vt  = (unsigned short*)(ws + (4ull << 20));          // 2 MB
  unsigned long long* Mk = (unsigned long long*)(ws + (6ull << 20));   // 1 MB
  unsigned short* Wob = (unsigned short*)(ws + (7ull << 20));          // 128 KB
  unsigned short* AOb = (unsigned short*)(ws + (8ull << 20));          // 2 MB

  build_mask<<<dim3(1088), 256, 0, stream>>>(adj, Mk, Wo, Wob);
  qkv_gemm<<<dim3(768), 256, 0, stream>>>(x, Wq, Wk, Wv, Qb, Kb, Vt);
  attn<<<dim3(1024), 512, 0, stream>>>(Qb, Kb, Vt, Mk, AOb);
  out_proj<<<dim3(256), 256, 0, stream>>>(AOb, Wob, bo, out);
}